// Round 12
// baseline (111.216 us; speedup 1.0000x reference)
//
#include <hip/hip_runtime.h>
#include <hip/hip_bf16.h>
#include <math.h>

#define NCAP 10
#define DCAP 16
#define DIN  128
#define NPOS 4096
#define NB   64

typedef short short8 __attribute__((ext_vector_type(8)));
typedef float floatx4 __attribute__((ext_vector_type(4)));

__device__ inline float bflo(unsigned v) { return __uint_as_float(v << 16); }
__device__ inline float bfhi(unsigned v) { return __uint_as_float(v & 0xFFFF0000u); }
__device__ inline unsigned short f2bf(float f) {           // round-to-nearest-even
    unsigned u = __float_as_uint(f);
    return (unsigned short)((u + 0x7FFFu + ((u >> 16) & 1u)) >> 16);
}
__device__ inline float bf2f(unsigned short h) { return __uint_as_float(((unsigned)h) << 16); }

// ===========================================================================
// BIG PATH (ws >= 85,147,648 B)
//   partial : f32 [64][16][128]   @ 0         (per-block col-sums of u, 512 KB)
//   vbuf    : f32 [64][10][16]    @ 524288
//   pws     : f32 [64][16][160]   @ 565248    (per-block partial c*u_hat sums)
//   WTg     : bf16 swizzled W     @ 1220608   (40960 B: [160 rows][16 chunks])
//   uhat    : bf16 [64][4096][160]@ 1261568   (u @ W, 83.9 MB)
// ===========================================================================

// One-time: pre-swizzle W (f32 [128][160]) -> WTg rows=out-col, 16 chunks of
// 8 k's, chunk index stored at (kc ^ (row&15)). Matches gemm's B-frag read.
__global__ __launch_bounds__(256) void wprep(const float* __restrict__ W,
                                             uint4* __restrict__ WTg) {
    const int cid = blockIdx.x * 256 + threadIdx.x;   // 2560 chunks
    if (cid >= 2560) return;
    const int row = cid >> 4;
    const int csn = cid & 15;
    const int kc = csn ^ (row & 15);
    unsigned p[4];
    #pragma unroll
    for (int e = 0; e < 4; ++e) {
        const float a = W[(kc * 8 + e * 2) * 160 + row];
        const float b = W[(kc * 8 + e * 2 + 1) * 160 + row];
        p[e] = (unsigned)f2bf(a) | ((unsigned)f2bf(b) << 16);
    }
    WTg[cid] = make_uint4(p[0], p[1], p[2], p[3]);
}

// u_hat = u @ W via bf16 MFMA. Block 256 thr / 4 waves, 256 positions.
// A-frags loaded directly from global (no in-staging); col-sums accumulated
// from the same registers. C staged through 32-pos LDS halves (52 KB total
// LDS -> 3 blocks/CU).
__global__ __launch_bounds__(256, 3) void gemm_uhat(const float* __restrict__ u,
                                                    const uint4* __restrict__ WTg,
                                                    uint4* __restrict__ uhat4,
                                                    float* __restrict__ partial) {
    const int b = blockIdx.x;
    const int blk = blockIdx.y;            // 16 blocks per b, 256 pos each
    const int t = threadIdx.x;
    const int l = t & 63;
    const int wv = __builtin_amdgcn_readfirstlane(t >> 6);

    __shared__ __align__(16) char lds[40960 + 11264];
    uint4* WT4 = (uint4*)lds;              // 2560 uint4
    short* out16 = (short*)(lds + 40960);  // [32 pos][176 shorts] (352 B rows)
    float* csbuf = (float*)(lds + 40960);  // reuse after last stage-out

    // ---- stage pre-swizzled W: coalesced, conflict-free ----
    #pragma unroll
    for (int i = 0; i < 10; ++i)
        WT4[t + i * 256] = WTg[t + i * 256];
    __syncthreads();

    float cs[4][8];
    #pragma unroll
    for (int kk = 0; kk < 4; ++kk)
        #pragma unroll
        for (int e = 0; e < 8; ++e) cs[kk][e] = 0.f;

    const short8* wt8 = (const short8*)lds;
    const float4* u4g = (const float4*)u;

    for (int mt = 0; mt < 4; ++mt) {
        // ---- A-frags direct from global + convert + col-sum ----
        const size_t row = (size_t)b * NPOS + blk * 256 + mt * 64 + wv * 16 + (l & 15);
        short8 af[4];
        #pragma unroll
        for (int kk = 0; kk < 4; ++kk) {
            const float4 x0 = u4g[row * 32 + kk * 8 + (l >> 4) * 2];
            const float4 x1 = u4g[row * 32 + kk * 8 + (l >> 4) * 2 + 1];
            cs[kk][0] += x0.x; cs[kk][1] += x0.y; cs[kk][2] += x0.z; cs[kk][3] += x0.w;
            cs[kk][4] += x1.x; cs[kk][5] += x1.y; cs[kk][6] += x1.z; cs[kk][7] += x1.w;
            short8 a;
            a[0] = (short)f2bf(x0.x); a[1] = (short)f2bf(x0.y);
            a[2] = (short)f2bf(x0.z); a[3] = (short)f2bf(x0.w);
            a[4] = (short)f2bf(x1.x); a[5] = (short)f2bf(x1.y);
            a[6] = (short)f2bf(x1.z); a[7] = (short)f2bf(x1.w);
            af[kk] = a;
        }

        // ---- MFMA: 10 n-tiles x K=128 ----
        floatx4 acc[10];
        #pragma unroll
        for (int n = 0; n < 10; ++n) {
            floatx4 a = {0.f, 0.f, 0.f, 0.f};
            #pragma unroll
            for (int kk = 0; kk < 4; ++kk) {
                const short8 bf = wt8[(n * 16 + (l & 15)) * 16 +
                                      ((kk * 4 + (l >> 4)) ^ (l & 15))];
                a = __builtin_amdgcn_mfma_f32_16x16x32_bf16(af[kk], bf, a, 0, 0, 0);
            }
            acc[n] = a;
        }

        // ---- C staging in two 32-pos halves ----
        #pragma unroll
        for (int h = 0; h < 2; ++h) {
            __syncthreads();               // out-LDS free (prev readers done)
            if ((wv >> 1) == h) {
                const int r0 = (wv & 1) * 16 + (l >> 4) * 4;  // local row base
                #pragma unroll
                for (int n = 0; n < 10; ++n)
                    #pragma unroll
                    for (int reg = 0; reg < 4; ++reg)
                        out16[(r0 + reg) * 176 + n * 16 + (l & 15)] =
                            (short)f2bf(acc[n][reg]);
            }
            __syncthreads();
            // stage out 32 pos x 20 uint4 (640 chunks), coalesced
            const uint4* o4 = (const uint4*)out16;
            const size_t gb = ((size_t)b * NPOS + blk * 256 + mt * 64 + h * 32) * 20;
            #pragma unroll
            for (int i = 0; i < 3; ++i) {
                const int q = t + i * 256;
                if (q < 640)
                    uhat4[gb + q] = o4[(q / 20) * 22 + (q % 20)];
            }
        }
    }

    // ---- fold col-sums: 16 row-lanes -> group value; 4 waves via LDS ----
    __syncthreads();                       // last stage-out readers done
    #pragma unroll
    for (int kk = 0; kk < 4; ++kk)
        #pragma unroll
        for (int e = 0; e < 8; ++e) {
            float v = cs[kk][e];
            v += __shfl_xor(v, 1); v += __shfl_xor(v, 2);
            v += __shfl_xor(v, 4); v += __shfl_xor(v, 8);
            cs[kk][e] = v;
        }
    if ((l & 15) == 0) {
        #pragma unroll
        for (int kk = 0; kk < 4; ++kk)
            #pragma unroll
            for (int e = 0; e < 8; ++e)
                csbuf[wv * 128 + kk * 32 + (l >> 4) * 8 + e] = cs[kk][e];
    }
    __syncthreads();
    if (t < 128)
        partial[(size_t)(b * 16 + blk) * 128 + t] =
            csbuf[t] + csbuf[128 + t] + csbuf[256 + t] + csbuf[384 + t];
}

// v1 from col-sum partials: s1 = 0.1 * (sum_i u) @ W -> squash -> vbuf.
__global__ __launch_bounds__(128) void small0(const float* __restrict__ partial,
                                              const float* __restrict__ W,
                                              float* __restrict__ vbuf) {
    const int b = blockIdx.x / NCAP;
    const int n = blockIdx.x % NCAP;
    const int t = threadIdx.x;
    __shared__ float xv[DIN];
    float a = 0.f;
    #pragma unroll 4
    for (int c = 0; c < 16; ++c)
        a += partial[(size_t)(b * 16 + c) * DIN + t];
    xv[t] = a;
    __syncthreads();
    if (t < DCAP) {
        float sv = 0.f;
        for (int d = 0; d < DIN; ++d)
            sv = fmaf(xv[d], W[d * 160 + n * DCAP + t], sv);
        sv *= 0.1f;
        float nq = sv * sv;
        #pragma unroll
        for (int mm = 8; mm >= 1; mm >>= 1) nq += __shfl_xor(nq, mm, 16);
        nq += 1e-7f;
        vbuf[(size_t)(b * NCAP + n) * DCAP + t] = sv * sqrtf(nq) / (1.0f + nq);
    }
}

// Routing on u_hat (unchanged from R10): per position 10 16-dim dots with v,
// softmax, accumulate c[n]*u_hat into per-block 160-f32 partial.
__global__ __launch_bounds__(256, 4) void route_uhat(const uint4* __restrict__ uhat4,
                                                     const float* __restrict__ vbuf,
                                                     float* __restrict__ pws) {
    const int b = blockIdx.x;
    const int blk = blockIdx.y;            // 16 per b, 256 pos each
    const int t = threadIdx.x;
    const int l = t & 63;
    const int wv = __builtin_amdgcn_readfirstlane(t >> 6);

    __shared__ __align__(16) char tl[64 * 336];  // [64 pos][168 shorts] padded
    __shared__ float lgp[4][64][10];
    __shared__ float cs[64][10];
    short* tls = (short*)tl;
    uint4* tl4 = (uint4*)tl;

    const float* vb = vbuf + (size_t)b * 160;    // uniform -> scalar loads
    float acc = 0.f;

    for (int s = 0; s < 4; ++s) {
        __syncthreads();                   // prev p2 reads done
        const size_t base4 = ((size_t)b * NPOS + blk * 256 + s * 64) * 20;
        #pragma unroll
        for (int i = 0; i < 5; ++i) {
            const int q = t + i * 256;     // 1280 chunks
            tl4[(q / 20) * 21 + (q % 20)] = uhat4[base4 + q];
        }
        __syncthreads();

        // ---- p1: lane = pos, wave = d-quarter ----
        float lg[10];
        #pragma unroll
        for (int n = 0; n < 10; ++n) {
            const uint2 uu = *(const uint2*)&tls[l * 168 + n * 16 + wv * 4];
            lg[n] = bflo(uu.x) * vb[n * 16 + wv * 4]
                  + bfhi(uu.x) * vb[n * 16 + wv * 4 + 1]
                  + bflo(uu.y) * vb[n * 16 + wv * 4 + 2]
                  + bfhi(uu.y) * vb[n * 16 + wv * 4 + 3];
            lgp[wv][l][n] = lg[n];
        }
        __syncthreads();

        // ---- fold + softmax (redundant per wave); wave 0 publishes c ----
        float c[10];
        float m = -1e30f;
        #pragma unroll
        for (int n = 0; n < 10; ++n) {
            c[n] = lgp[0][l][n] + lgp[1][l][n] + lgp[2][l][n] + lgp[3][l][n];
            m = fmaxf(m, c[n]);
        }
        float ssum = 0.f;
        #pragma unroll
        for (int n = 0; n < 10; ++n) { c[n] = __expf(c[n] - m); ssum += c[n]; }
        const float inv = 1.0f / ssum;
        if (wv == 0) {
            #pragma unroll
            for (int n = 0; n < 10; ++n) cs[l][n] = c[n] * inv;
        }
        __syncthreads();

        // ---- p2: thread t<160 owns (n,d), sums all 64 positions ----
        if (t < 160) {
            const int n = t >> 4;
            for (int p = 0; p < 64; ++p)
                acc = fmaf(cs[p][n], bf2f((unsigned short)tls[p * 168 + t]), acc);
        }
    }
    if (t < 160) pws[(size_t)(b * 16 + blk) * 160 + t] = acc;
}

// Fold 16 block-partials -> s -> squash -> v (dst = vbuf or out).
__global__ __launch_bounds__(256) void smallv(const float* __restrict__ pws,
                                              float* __restrict__ dst) {
    const int b = blockIdx.x;
    const int t = threadIdx.x;
    if (t >= 160) return;
    float a = 0.f;
    #pragma unroll
    for (int c = 0; c < 16; ++c)
        a += pws[(size_t)(b * 16 + c) * 160 + t];
    float nq = a * a;
    #pragma unroll
    for (int mm = 8; mm >= 1; mm >>= 1) nq += __shfl_xor(nq, mm, 16);
    nq += 1e-7f;
    dst[(size_t)b * 160 + t] = a * sqrtf(nq) / (1.0f + nq);
}

// ===========================================================================
// FALLBACK PATH (R7, verified): f32 routing against w = W @ v.
// ===========================================================================

__global__ __launch_bounds__(256) void caps_sum(const float* __restrict__ u,
                                                float* __restrict__ partial) {
    const int b = blockIdx.x;
    const int chunk = blockIdx.y;
    const int t = threadIdx.x;
    const int v4 = t & 31;
    const int prow = t >> 5;
    const float4* up = (const float4*)u;
    const size_t posbase = (size_t)b * NPOS + chunk * 256;
    float4 acc = make_float4(0.f, 0.f, 0.f, 0.f);
    #pragma unroll 8
    for (int j = 0; j < 32; ++j) {
        float4 x = up[(posbase + prow + j * 8) * 32 + v4];
        acc.x += x.x; acc.y += x.y; acc.z += x.z; acc.w += x.w;
    }
    __shared__ float4 red[8][32];
    red[prow][v4] = acc;
    __syncthreads();
    if (t < 32) {
        float4 s = red[0][t];
        #pragma unroll
        for (int r = 1; r < 8; ++r) {
            s.x += red[r][t].x; s.y += red[r][t].y;
            s.z += red[r][t].z; s.w += red[r][t].w;
        }
        ((float4*)partial)[((size_t)b * 16 + chunk) * 32 + t] = s;
    }
}

template <int MODE>
__global__ __launch_bounds__(128) void caps_small(const float* __restrict__ src,
                                                  const float* __restrict__ W,
                                                  float* __restrict__ dst) {
    const int b = blockIdx.x / NCAP;
    const int n = blockIdx.x % NCAP;
    const int t = threadIdx.x;
    __shared__ float xv[DIN];
    __shared__ float vv[DCAP];
    float a = 0.f;
    if (MODE == 0) {
        #pragma unroll 4
        for (int c = 0; c < 16; ++c) a += src[(size_t)(b * 16 + c) * DIN + t];
    } else {
        #pragma unroll 4
        for (int c = 0; c < 16; ++c) a += src[((size_t)(b * 16 + c) * NCAP + n) * DIN + t];
    }
    xv[t] = a;
    __syncthreads();
    if (t < DCAP) {
        float sv = 0.f;
        for (int d = 0; d < DIN; ++d) sv = fmaf(xv[d], W[d * 160 + n * DCAP + t], sv);
        if (MODE == 0) sv *= 0.1f;
        float nq = sv * sv;
        #pragma unroll
        for (int mm = 8; mm >= 1; mm >>= 1) nq += __shfl_xor(nq, mm, 16);
        nq += 1e-7f;
        const float v = sv * sqrtf(nq) / (1.0f + nq);
        if (MODE == 2) dst[(size_t)(b * NCAP + n) * DCAP + t] = v;
        else vv[t] = v;
    }
    if (MODE != 2) {
        __syncthreads();
        float wd = 0.f;
        #pragma unroll
        for (int dd = 0; dd < DCAP; ++dd)
            wd = fmaf(W[t * 160 + n * DCAP + dd], vv[dd], wd);
        dst[(size_t)(b * NCAP + n) * DIN + t] = wd;
    }
}

__global__ __launch_bounds__(256, 3) void caps_route(const float* __restrict__ u,
                                                     const float* __restrict__ wsrc,
                                                     float* __restrict__ pdst) {
    const int b = blockIdx.x;
    const int tile = blockIdx.y;
    const int t = threadIdx.x;
    const int lane = t & 63;
    const int wv = __builtin_amdgcn_readfirstlane(t >> 6);
    __shared__ float4 tl4[64 * 32];
    __shared__ float lgp[4][64][11];
    float* tlf = (float*)tl4;
    const float4* wq4 = (const float4*)(wsrc + (size_t)b * (NCAP * DIN));
    float acc0[NCAP], acc1[NCAP];
    #pragma unroll
    for (int n = 0; n < NCAP; ++n) { acc0[n] = 0.f; acc1[n] = 0.f; }
    for (int s = 0; s < 4; ++s) {
        __syncthreads();
        const float4* src4 = (const float4*)u + ((size_t)b * NPOS + tile * 256 + s * 64) * 32;
        #pragma unroll
        for (int i = 0; i < 8; ++i) {
            const int q = t + i * 256;
            const int r = q >> 5, c = q & 31;
            tl4[r * 32 + (c ^ (r & 7))] = src4[q];
        }
        __syncthreads();
        float lg[NCAP];
        #pragma unroll
        for (int n = 0; n < NCAP; ++n) lg[n] = 0.f;
        #pragma unroll
        for (int j = 0; j < 8; ++j) {
            const float4 u4 = tl4[lane * 32 + wv * 8 + (j ^ (lane & 7))];
            #pragma unroll
            for (int n = 0; n < NCAP; ++n) {
                const float4 w4 = wq4[n * 32 + wv * 8 + j];
                lg[n] = fmaf(u4.x, w4.x, fmaf(u4.y, w4.y,
                        fmaf(u4.z, w4.z, fmaf(u4.w, w4.w, lg[n]))));
            }
        }
        #pragma unroll
        for (int n = 0; n < NCAP; ++n) lgp[wv][lane][n] = lg[n];
        __syncthreads();
        float c[NCAP];
        float m = -1e30f;
        #pragma unroll
        for (int n = 0; n < NCAP; ++n) {
            c[n] = lgp[0][lane][n] + lgp[1][lane][n] + lgp[2][lane][n] + lgp[3][lane][n];
            m = fmaxf(m, c[n]);
        }
        float ssum = 0.f;
        #pragma unroll
        for (int n = 0; n < NCAP; ++n) { c[n] = __expf(c[n] - m); ssum += c[n]; }
        const float inv = 1.0f / ssum;
        #pragma unroll
        for (int n = 0; n < NCAP; ++n) c[n] *= inv;
        const int col0 = lane >> 2, word = lane & 3;
        #pragma unroll
        for (int i = 0; i < 16; ++i) {
            const int p = wv * 16 + i;
            const int ca = col0 ^ (p & 7);
            const float u0 = tlf[(p * 32 + ca) * 4 + word];
            const float u1 = tlf[(p * 32 + ca + 16) * 4 + word];
            #pragma unroll
            for (int n = 0; n < NCAP; ++n) {
                const float cp = __int_as_float(
                    __builtin_amdgcn_readlane(__float_as_int(c[n]), p));
                acc0[n] = fmaf(cp, u0, acc0[n]);
                acc1[n] = fmaf(cp, u1, acc1[n]);
            }
        }
    }
    __syncthreads();
    float* red = tlf;
    #pragma unroll
    for (int n = 0; n < NCAP; ++n) {
        red[(wv * NCAP + n) * DIN + lane]      = acc0[n];
        red[(wv * NCAP + n) * DIN + lane + 64] = acc1[n];
    }
    __syncthreads();
    float* pb = pdst + (size_t)(b * 16 + tile) * (NCAP * DIN);
    for (int k = t; k < NCAP * DIN; k += 256)
        pb[k] = red[k] + red[1280 + k] + red[2560 + k] + red[3840 + k];
}

extern "C" void kernel_launch(void* const* d_in, const int* in_sizes, int n_in,
                              void* d_out, int out_size, void* d_ws, size_t ws_size,
                              hipStream_t stream) {
    const float* u = (const float*)d_in[0];   // [64][4096][128]
    const float* W = (const float*)d_in[1];   // [128][160]
    float* out = (float*)d_out;               // [64][10][16]
    char* wsb = (char*)d_ws;

    if (ws_size >= 85147648ull) {
        float* partial = (float*)wsb;                       // 512 KB
        float* vbuf    = (float*)(wsb + 524288);            // 40 KB
        float* pws     = (float*)(wsb + 565248);            // 640 KB
        uint4* WTg     = (uint4*)(wsb + 1220608);           // 40 KB
        uint4* uhat    = (uint4*)(wsb + 1261568);           // 83.9 MB bf16

        wprep<<<10, 256, 0, stream>>>(W, WTg);
        gemm_uhat<<<dim3(NB, 16), 256, 0, stream>>>(u, WTg, uhat, partial);
        small0<<<NB * NCAP, 128, 0, stream>>>(partial, W, vbuf);       // v1
        route_uhat<<<dim3(NB, 16), 256, 0, stream>>>(uhat, vbuf, pws); // iter 2
        smallv<<<NB, 256, 0, stream>>>(pws, vbuf);                     // v2
        route_uhat<<<dim3(NB, 16), 256, 0, stream>>>(uhat, vbuf, pws); // iter 3
        smallv<<<NB, 256, 0, stream>>>(pws, out);                      // v3 -> out
    } else {
        float* partial = (float*)wsb;
        float* wbuf    = (float*)wsb + 131072;
        float* pws32   = (float*)wsb + 212992;
        caps_sum<<<dim3(NB, 16), 256, 0, stream>>>(u, partial);
        caps_small<0><<<NB * NCAP, 128, 0, stream>>>(partial, W, wbuf);
        caps_route<<<dim3(NB, 16), 256, 0, stream>>>(u, wbuf, pws32);
        caps_small<1><<<NB * NCAP, 128, 0, stream>>>(pws32, W, wbuf);
        caps_route<<<dim3(NB, 16), 256, 0, stream>>>(u, wbuf, pws32);
        caps_small<2><<<NB * NCAP, 128, 0, stream>>>(pws32, W, out);
    }
}